// Round 11
// baseline (159.323 us; speedup 1.0000x reference)
//
#include <hip/hip_runtime.h>
#include <hip/hip_bf16.h>

typedef __hip_bfloat16 bf16;
typedef __attribute__((ext_vector_type(8))) short short8v;   // bf16x8 MFMA fragment
typedef __attribute__((ext_vector_type(4))) float f32x4;     // MFMA accumulator

#define NJ   17
#define ND   128
#define NP   6
#define NH   4
#define NBT  16384
#define NG   4               // frames per block
#define NTOK (NG*NP)         // 24 tokens
#define NTHR 512             // 8 waves
#define GRID (NBT/NG)        // 4096 blocks
#define TSTR 136             // bf16 row stride: 272B
#define YSTR 132             // y fp32 row stride

// ws layout: bf16 wgt[81920] | fp32 bc[384] @163840 | u32 mb[16384] @165376
#define WS_WP 0
#define WS_WC 16384
#define WS_WO 65536
#define WS_BC 163840
#define WS_MB 165376

// LDS arena offsets (bytes)
#define OFF_POOL 0            // [24][136] bf16
#define OFF_Q    6528         // [24][136] bf16 ; o overwrites q after PV
#define OFF_K    13056        // [24][136] bf16 ; dead after scores
#define OFF_V    19584        // [24][136] bf16 ; dead after PV
#define OFF_Y    13056        // [24][132] fp32 = 12672 aliases k|v (ends 25728)
#define OFF_PROB 26112        // [4][4][6][6] fp32 = 2304 B
#define ARENA_SZ 28416

__device__ __forceinline__ float bf2f(unsigned short u) {
    return __uint_as_float(((unsigned)u) << 16);
}
__device__ __forceinline__ unsigned pk2(float x, float y) {
    bf16 bx = __float2bfloat16(x), by = __float2bfloat16(y);
    unsigned short ux = *reinterpret_cast<unsigned short*>(&bx);
    unsigned short uy = *reinterpret_cast<unsigned short*>(&by);
    return ((unsigned)uy << 16) | ux;
}
__device__ __forceinline__ f32x4 MFMA(short8v a, short8v b, f32x4 c) {
    return __builtin_amdgcn_mfma_f32_16x16x32_bf16(a, b, c, 0, 0, 0);
}
__device__ __forceinline__ short8v ldB(const bf16* __restrict__ W, int nt, int ks, int lane) {
    return *reinterpret_cast<const short8v*>(W + (nt*16 + (lane & 15))*ND + ks*32 + ((lane >> 4) << 3));
}
__device__ __forceinline__ short8v ldsA(const bf16* __restrict__ s, int mt, int ks, int lane) {
    int row = mt*16 + (lane & 15);
    if (row >= NTOK) row = NTOK - 1;
    return *reinterpret_cast<const short8v*>(s + row*TSTR + ks*32 + ((lane >> 4) << 3));
}
// Block barrier with LDS ordering only — global loads stay in flight.
__device__ __forceinline__ void bsync() {
    asm volatile("s_waitcnt lgkmcnt(0)" ::: "memory");
    __builtin_amdgcn_s_barrier();
    asm volatile("" ::: "memory");
}
// Intra-wave LDS write->read fence (rule #18: sched_barrier after lgkmcnt).
#define WFENCE() do { \
    asm volatile("s_waitcnt lgkmcnt(0)" ::: "memory"); \
    __builtin_amdgcn_sched_barrier(0); \
} while (0)

// ---- fused prep (validated): Wp/Wo bf16 + Wc = Win@Wp + bc + mask bits ----
extern "C" __global__ __launch_bounds__(128)
void prep(const float* __restrict__ Wp, const float* __restrict__ Wi,
          const float* __restrict__ Wo, const float* __restrict__ bp,
          const float* __restrict__ bi, const float* __restrict__ mask,
          bf16* __restrict__ wgt, float* __restrict__ bc,
          unsigned* __restrict__ mbuf) {
    const int b = blockIdx.x, t = threadIdx.x;
    if (b < 384) {
        __shared__ float s_wi[128];
        __shared__ float s_red[128];
        s_wi[t] = Wi[b*128 + t];
        __syncthreads();
        float acc = 0.f;
        #pragma unroll 8
        for (int m = 0; m < 128; ++m)
            acc = fmaf(s_wi[m], Wp[m*128 + t], acc);
        wgt[WS_WC + b*128 + t] = __float2bfloat16(acc);
        s_red[t] = s_wi[t] * bp[t];
        __syncthreads();
        #pragma unroll
        for (int s = 64; s > 0; s >>= 1) {
            if (t < s) s_red[t] += s_red[t+s];
            __syncthreads();
        }
        if (t == 0) bc[b] = s_red[0] + bi[b];
    } else {
        int gid = (b - 384)*128 + t;          // 0..32767
        if (gid < 16384) wgt[WS_WP + gid] = __float2bfloat16(Wp[gid]);
        else             wgt[WS_WO + (gid - 16384)] = __float2bfloat16(Wo[gid - 16384]);
        if (gid < 16384) {
            const float* m = mask + (long)gid*NJ;
            unsigned bb = 0;
            #pragma unroll
            for (int j = 0; j < NJ; ++j)
                bb |= (m[j] > 0.05f) ? (1u << j) : 0u;
            mbuf[gid] = bb;
        }
    }
}

// Store a 24-row C column slice (2 M-tiles) to a [24][TSTR] bf16 buffer.
__device__ __forceinline__ void st24(bf16* __restrict__ dst, const f32x4 &a0,
                                     const f32x4 &a1, float bv, int col, int lhi) {
    #pragma unroll
    for (int j = 0; j < 4; ++j) {
        int r0 = lhi*4 + j;
        dst[r0*TSTR + col] = __float2bfloat16(a0[j] + bv);
        int r1 = 16 + lhi*4 + j;
        if (r1 < NTOK) dst[r1*TSTR + col] = __float2bfloat16(a1[j] + bv);
    }
}

extern "C" __global__ __launch_bounds__(NTHR, 8)
void bpa_fused(const float* __restrict__ h_joint,
               const bf16* __restrict__ wgt, const float* __restrict__ bc,
               const unsigned* __restrict__ mbuf,
               const float* __restrict__ b_proj, const float* __restrict__ b_out,
               const float* __restrict__ ln_g,  const float* __restrict__ ln_b,
               float* __restrict__ out)
{
    __shared__ __align__(16) unsigned char s_arena[ARENA_SZ];
    bf16*  s_pool  = reinterpret_cast<bf16*>(s_arena + OFF_POOL);
    bf16*  s_q     = reinterpret_cast<bf16*>(s_arena + OFF_Q);
    bf16*  s_k     = reinterpret_cast<bf16*>(s_arena + OFF_K);
    bf16*  s_v     = reinterpret_cast<bf16*>(s_arena + OFF_V);
    float* s_y     = reinterpret_cast<float*>(s_arena + OFF_Y);
    float* s_probs = reinterpret_cast<float*>(s_arena + OFF_PROB);

    const int tid  = threadIdx.x;
    const int lane = tid & 63;
    const int w    = tid >> 6;                          // wave 0..7
    const int l15  = lane & 15;
    const int lhi  = lane >> 4;                         // 0..3
    const long frame0 = (long)blockIdx.x * NG;

    // ---- Stage 1: pooling (thread = (frame f, col d)), unconditional loads ----
    {
        const int f = tid >> 7;
        const int d = tid & (ND-1);
        const float* hcol = h_joint + (frame0 + f)*(long)(NJ*ND) + d;
        float hv[NJ];
        #pragma unroll
        for (int j = 0; j < NJ; ++j) hv[j] = hcol[j*ND];
        unsigned mb = mbuf[frame0 + f];
        #pragma unroll
        for (int j = 0; j < NJ; ++j)
            hv[j] = (mb >> j & 1) ? hv[j] : 0.f;
        float acc[NP];
        acc[0] = ((hv[0]+hv[1]) + (hv[2]+hv[3])) + hv[4];
        acc[1] = (hv[5]+hv[6]) + (hv[11]+hv[12]);
        acc[2] = hv[5]+hv[7]+hv[9];
        acc[3] = hv[6]+hv[8]+hv[10];
        acc[4] = hv[11]+hv[13]+hv[15];
        acc[5] = hv[12]+hv[14]+hv[16];
        const unsigned pm[NP] = {0x1Fu, 0x1860u, 0x2A0u, 0x540u, 0xA800u, 0x15000u};
        #pragma unroll
        for (int p = 0; p < NP; ++p) {
            float cnt = (float)__popc(mb & pm[p]);
            s_pool[(f*NP+p)*TSTR + d] = __float2bfloat16(acc[p] / fmaxf(cnt, 1e-6f));
        }
    }
    bsync();   // B1

    // ---- Stage 2: tok (REGISTERS) + q,k,v (LDS), double-buffered B prefetch ----
    f32x4 tk0 = (f32x4)(0.f), tk1 = (f32x4)(0.f);       // tok fragments (resid)
    {
        short8v bA[4], bB[4];
        #pragma unroll
        for (int ks = 0; ks < 4; ++ks) bA[ks] = ldB(wgt + WS_WP, w, ks, lane);
        #pragma unroll
        for (int ks = 0; ks < 4; ++ks) bB[ks] = ldB(wgt + WS_WC, w, ks, lane);   // q
        // tok (bA) -> registers, no bias (folded in stage 4)
        #pragma unroll
        for (int ks = 0; ks < 4; ++ks) {
            tk0 = MFMA(ldsA(s_pool, 0, ks, lane), bA[ks], tk0);
            tk1 = MFMA(ldsA(s_pool, 1, ks, lane), bA[ks], tk1);
        }
        #pragma unroll
        for (int ks = 0; ks < 4; ++ks) bA[ks] = ldB(wgt + WS_WC, 8 + w, ks, lane);  // k
        const int col = w*16 + l15;
        // q (bB)
        {
            f32x4 a0 = (f32x4)(0.f), a1 = (f32x4)(0.f);
            #pragma unroll
            for (int ks = 0; ks < 4; ++ks) {
                a0 = MFMA(ldsA(s_pool, 0, ks, lane), bB[ks], a0);
                a1 = MFMA(ldsA(s_pool, 1, ks, lane), bB[ks], a1);
            }
            st24(s_q, a0, a1, bc[w*16 + l15], col, lhi);
        }
        #pragma unroll
        for (int ks = 0; ks < 4; ++ks) bB[ks] = ldB(wgt + WS_WC, 16 + w, ks, lane); // v
        // k (bA)
        {
            f32x4 a0 = (f32x4)(0.f), a1 = (f32x4)(0.f);
            #pragma unroll
            for (int ks = 0; ks < 4; ++ks) {
                a0 = MFMA(ldsA(s_pool, 0, ks, lane), bA[ks], a0);
                a1 = MFMA(ldsA(s_pool, 1, ks, lane), bA[ks], a1);
            }
            st24(s_k, a0, a1, bc[(8+w)*16 + l15], col, lhi);
        }
        // v (bB)
        {
            f32x4 a0 = (f32x4)(0.f), a1 = (f32x4)(0.f);
            #pragma unroll
            for (int ks = 0; ks < 4; ++ks) {
                a0 = MFMA(ldsA(s_pool, 0, ks, lane), bB[ks], a0);
                a1 = MFMA(ldsA(s_pool, 1, ks, lane), bB[ks], a1);
            }
            st24(s_v, a0, a1, bc[(16+w)*16 + l15], col, lhi);
        }
    }
    bsync();   // B2

    // ---- Stage 3 (waves 0..3, wave fq owns frame fq): MFMA scores + wave-parallel
    //      softmax + importance + PV, all intra-wave (WFENCE only) ----
    if (w < NG) {
        const int fq = w;
        float* s_pr = s_probs + fq*(NH*NP*NP);
        const int arow = (fq*NP + (l15 > 5 ? 5 : l15))*TSTR + (lhi << 3);
        float imp = 0.f;
        #pragma unroll
        for (int h = 0; h < NH; ++h) {
            short8v qa = *reinterpret_cast<const short8v*>(s_q + arow + h*32);
            short8v kb = *reinterpret_cast<const short8v*>(s_k + arow + h*32);
            f32x4 c = MFMA(qa, kb, (f32x4)(0.f));
            #pragma unroll
            for (int j = 0; j < 4; ++j) {
                int q = lhi*4 + j;
                float sc  = c[j] * 0.17677669529663688f;     // 1/sqrt(32)
                float scm = (l15 < NP) ? sc : -1e30f;
                scm = fmaxf(scm, __shfl_xor(scm, 1));
                scm = fmaxf(scm, __shfl_xor(scm, 2));
                scm = fmaxf(scm, __shfl_xor(scm, 4));
                scm = fmaxf(scm, __shfl_xor(scm, 8));
                float e = (l15 < NP) ? __expf(sc - scm) : 0.f;
                float den = e;
                den += __shfl_xor(den, 1);
                den += __shfl_xor(den, 2);
                den += __shfl_xor(den, 4);
                den += __shfl_xor(den, 8);
                float p = e / den;
                if (q < NP) {
                    imp += p;                                 // p==0 for l15>=6
                    if (l15 < NP) s_pr[(h*NP + q)*NP + l15] = p;
                }
            }
        }
        imp += __shfl_xor(imp, 16);
        imp += __shfl_xor(imp, 32);
        if (lane < NP)
            out[(long)NBT*NP*ND + (frame0 + fq)*NP + lane] = imp * (1.f/24.f);
        WFENCE();   // P visible within wave
        // PV: lane owns cols c0,c0+1 (head h = lane>>4); o over dead q rows
        {
            const int c0 = lane*2;
            const int h  = lane >> 4;
            const float* pr = s_pr + h*NP*NP;
            float vx[NP], vy[NP];
            #pragma unroll
            for (int pk = 0; pk < NP; ++pk) {
                unsigned vv = *reinterpret_cast<const unsigned*>(&s_v[(fq*NP+pk)*TSTR + c0]);
                vx[pk] = bf2f((unsigned short)(vv & 0xFFFF));
                vy[pk] = bf2f((unsigned short)(vv >> 16));
            }
            #pragma unroll
            for (int qi = 0; qi < NP; ++qi) {
                const float* pq = pr + qi*NP;
                float ox = pq[0]*vx[0]+pq[1]*vx[1]+pq[2]*vx[2]
                         + pq[3]*vx[3]+pq[4]*vx[4]+pq[5]*vx[5];
                float oy = pq[0]*vy[0]+pq[1]*vy[1]+pq[2]*vy[2]
                         + pq[3]*vy[3]+pq[4]*vy[4]+pq[5]*vy[5];
                *reinterpret_cast<unsigned*>(&s_q[(fq*NP+qi)*TSTR + c0]) = pk2(ox, oy);
            }
        }
    }
    bsync();   // B3

    // ---- Stage 4: y = o @ Wo^T + (bp+bo) + tok -> fp32 y over dead k|v ----
    {
        short8v bo[4];
        #pragma unroll
        for (int ks = 0; ks < 4; ++ks) bo[ks] = ldB(wgt + WS_WO, w, ks, lane);
        f32x4 a0 = (f32x4)(0.f), a1 = (f32x4)(0.f);
        #pragma unroll
        for (int ks = 0; ks < 4; ++ks) {
            a0 = MFMA(ldsA(s_q, 0, ks, lane), bo[ks], a0);
            a1 = MFMA(ldsA(s_q, 1, ks, lane), bo[ks], a1);
        }
        int col = w*16 + l15;
        float bb = b_proj[col] + b_out[col];
        #pragma unroll
        for (int j = 0; j < 4; ++j) {
            int r0 = lhi*4 + j;
            s_y[r0*YSTR + col] = a0[j] + tk0[j] + bb;
            int r1 = 16 + lhi*4 + j;
            if (r1 < NTOK) s_y[r1*YSTR + col] = a1[j] + tk1[j] + bb;
        }
    }
    bsync();   // B4

    // ---- Stage 5: fused LayerNorm + store (wave w owns tokens 3w..3w+2) ----
    {
        const int c0 = lane*2;
        float2 g2 = *reinterpret_cast<const float2*>(ln_g + c0);
        float2 b2 = *reinterpret_cast<const float2*>(ln_b + c0);
        #pragma unroll
        for (int ti = 0; ti < 3; ++ti) {
            int token = w*3 + ti;
            float2 v = *reinterpret_cast<const float2*>(s_y + token*YSTR + c0);
            float s  = v.x + v.y;
            float s2 = v.x*v.x + v.y*v.y;
            s  += __shfl_xor(s, 1);  s  += __shfl_xor(s, 2);
            s  += __shfl_xor(s, 4);  s  += __shfl_xor(s, 8);
            s  += __shfl_xor(s, 16); s  += __shfl_xor(s, 32);
            s2 += __shfl_xor(s2, 1); s2 += __shfl_xor(s2, 2);
            s2 += __shfl_xor(s2, 4); s2 += __shfl_xor(s2, 8);
            s2 += __shfl_xor(s2, 16); s2 += __shfl_xor(s2, 32);
            float mean = s * (1.f/128.f);
            float rinv = rsqrtf(s2 * (1.f/128.f) - mean*mean + 1e-5f);
            float2 r;
            r.x = (v.x - mean)*rinv*g2.x + b2.x;
            r.y = (v.y - mean)*rinv*g2.y + b2.y;
            *reinterpret_cast<float2*>(out + (frame0*NP + token)*(long)ND + c0) = r;
        }
    }
}

extern "C" void kernel_launch(void* const* d_in, const int* in_sizes, int n_in,
                              void* d_out, int out_size, void* d_ws, size_t ws_size,
                              hipStream_t stream) {
    const float* h_joint = (const float*)d_in[0];
    const float* mask    = (const float*)d_in[1];
    const float* W_proj  = (const float*)d_in[2];
    const float* b_proj  = (const float*)d_in[3];
    const float* W_in    = (const float*)d_in[4];
    const float* b_in    = (const float*)d_in[5];
    const float* W_out   = (const float*)d_in[6];
    const float* b_out   = (const float*)d_in[7];
    const float* ln_g    = (const float*)d_in[8];
    const float* ln_b    = (const float*)d_in[9];
    float* out = (float*)d_out;
    bf16*     wgt  = (bf16*)d_ws;
    float*    bc   = (float*)((char*)d_ws + WS_BC);
    unsigned* mbuf = (unsigned*)((char*)d_ws + WS_MB);

    hipLaunchKernelGGL(prep, dim3(640), dim3(128), 0, stream,
                       W_proj, W_in, W_out, b_proj, b_in, mask, wgt, bc, mbuf);
    hipLaunchKernelGGL(bpa_fused, dim3(GRID), dim3(NTHR), 0, stream,
                       h_joint, wgt, bc, mbuf, b_proj, b_out, ln_g, ln_b, out);
}

// Round 12
// 139.922 us; speedup vs baseline: 1.1387x; 1.1387x over previous
//
#include <hip/hip_runtime.h>
#include <hip/hip_bf16.h>

typedef __hip_bfloat16 bf16;
typedef __attribute__((ext_vector_type(8))) short short8v;   // bf16x8 MFMA fragment
typedef __attribute__((ext_vector_type(4))) float f32x4;     // MFMA accumulator

#define NJ   17
#define ND   128
#define NP   6
#define NH   4
#define NBT  16384
#define NG   4               // frames per block
#define NTOK (NG*NP)         // 24 tokens
#define NTHR 512             // 8 waves
#define GRID (NBT/NG)        // 4096 blocks
#define TSTR 136             // bf16 row stride: 272B
#define YSTR 132             // y fp32 row stride

// ws layout: bf16 wgt[81920] | fp32 bc[384] @163840 | u32 mb[16384] @165376
#define WS_WP 0
#define WS_WC 16384
#define WS_WO 65536
#define WS_BC 163840
#define WS_MB 165376

// LDS arena offsets (bytes)
#define OFF_POOL 0            // [24][136] bf16
#define OFF_Q    6528         // [24][136] bf16 ; o overwrites q after PV
#define OFF_K    13056        // [24][136] bf16 ; dead after scores
#define OFF_V    19584        // [24][136] bf16 ; dead after PV
#define OFF_Y    13056        // [24][132] fp32 = 12672 aliases k|v (ends 25728)
#define OFF_PROB 26112        // [4][4][6][6] fp32 = 2304 B
#define ARENA_SZ 28416

__device__ __forceinline__ float bf2f(unsigned short u) {
    return __uint_as_float(((unsigned)u) << 16);
}
__device__ __forceinline__ f32x4 MFMA(short8v a, short8v b, f32x4 c) {
    return __builtin_amdgcn_mfma_f32_16x16x32_bf16(a, b, c, 0, 0, 0);
}
__device__ __forceinline__ short8v ldB(const bf16* __restrict__ W, int nt, int ks, int lane) {
    return *reinterpret_cast<const short8v*>(W + (nt*16 + (lane & 15))*ND + ks*32 + ((lane >> 4) << 3));
}
__device__ __forceinline__ short8v ldsA(const bf16* __restrict__ s, int mt, int ks, int lane) {
    int row = mt*16 + (lane & 15);
    if (row >= NTOK) row = NTOK - 1;
    return *reinterpret_cast<const short8v*>(s + row*TSTR + ks*32 + ((lane >> 4) << 3));
}
// Block barrier with LDS ordering only — global loads stay in flight.
__device__ __forceinline__ void bsync() {
    asm volatile("s_waitcnt lgkmcnt(0)" ::: "memory");
    __builtin_amdgcn_s_barrier();
    asm volatile("" ::: "memory");
}
// Intra-wave LDS write->read fence (rule #18: sched_barrier after lgkmcnt).
#define WFENCE() do { \
    asm volatile("s_waitcnt lgkmcnt(0)" ::: "memory"); \
    __builtin_amdgcn_sched_barrier(0); \
} while (0)

// ---- fused prep (validated): Wp/Wo bf16 + Wc = Win@Wp + bc + mask bits ----
extern "C" __global__ __launch_bounds__(128)
void prep(const float* __restrict__ Wp, const float* __restrict__ Wi,
          const float* __restrict__ Wo, const float* __restrict__ bp,
          const float* __restrict__ bi, const float* __restrict__ mask,
          bf16* __restrict__ wgt, float* __restrict__ bc,
          unsigned* __restrict__ mbuf) {
    const int b = blockIdx.x, t = threadIdx.x;
    if (b < 384) {
        __shared__ float s_wi[128];
        __shared__ float s_red[128];
        s_wi[t] = Wi[b*128 + t];
        __syncthreads();
        float acc = 0.f;
        #pragma unroll 8
        for (int m = 0; m < 128; ++m)
            acc = fmaf(s_wi[m], Wp[m*128 + t], acc);
        wgt[WS_WC + b*128 + t] = __float2bfloat16(acc);
        s_red[t] = s_wi[t] * bp[t];
        __syncthreads();
        #pragma unroll
        for (int s = 64; s > 0; s >>= 1) {
            if (t < s) s_red[t] += s_red[t+s];
            __syncthreads();
        }
        if (t == 0) bc[b] = s_red[0] + bi[b];
    } else {
        int gid = (b - 384)*128 + t;          // 0..32767
        if (gid < 16384) wgt[WS_WP + gid] = __float2bfloat16(Wp[gid]);
        else             wgt[WS_WO + (gid - 16384)] = __float2bfloat16(Wo[gid - 16384]);
        if (gid < 16384) {
            const float* m = mask + (long)gid*NJ;
            unsigned bb = 0;
            #pragma unroll
            for (int j = 0; j < NJ; ++j)
                bb |= (m[j] > 0.05f) ? (1u << j) : 0u;
            mbuf[gid] = bb;
        }
    }
}

// Store a 24-row C column slice (2 M-tiles) to a [24][TSTR] bf16 buffer.
__device__ __forceinline__ void st24(bf16* __restrict__ dst, const f32x4 &a0,
                                     const f32x4 &a1, float bv, int col, int lhi) {
    #pragma unroll
    for (int j = 0; j < 4; ++j) {
        int r0 = lhi*4 + j;
        dst[r0*TSTR + col] = __float2bfloat16(a0[j] + bv);
        int r1 = 16 + lhi*4 + j;
        if (r1 < NTOK) dst[r1*TSTR + col] = __float2bfloat16(a1[j] + bv);
    }
}

extern "C" __global__ __launch_bounds__(NTHR, 6)
void bpa_fused(const float* __restrict__ h_joint,
               const bf16* __restrict__ wgt, const float* __restrict__ bc,
               const unsigned* __restrict__ mbuf,
               const float* __restrict__ b_proj, const float* __restrict__ b_out,
               const float* __restrict__ ln_g,  const float* __restrict__ ln_b,
               float* __restrict__ out)
{
    __shared__ __align__(16) unsigned char s_arena[ARENA_SZ];
    bf16*  s_pool  = reinterpret_cast<bf16*>(s_arena + OFF_POOL);
    bf16*  s_q     = reinterpret_cast<bf16*>(s_arena + OFF_Q);
    bf16*  s_k     = reinterpret_cast<bf16*>(s_arena + OFF_K);
    bf16*  s_v     = reinterpret_cast<bf16*>(s_arena + OFF_V);
    float* s_y     = reinterpret_cast<float*>(s_arena + OFF_Y);
    float* s_probs = reinterpret_cast<float*>(s_arena + OFF_PROB);

    const int tid  = threadIdx.x;
    const int lane = tid & 63;
    const int w    = tid >> 6;                          // wave 0..7
    const int l15  = lane & 15;
    const int lhi  = lane >> 4;                         // 0..3
    const long frame0 = (long)blockIdx.x * NG;

    // ---- Stage 1: pooling (thread = (frame f, col d)), unconditional loads ----
    {
        const int f = tid >> 7;
        const int d = tid & (ND-1);
        const float* hcol = h_joint + (frame0 + f)*(long)(NJ*ND) + d;
        float hv[NJ];
        #pragma unroll
        for (int j = 0; j < NJ; ++j) hv[j] = hcol[j*ND];
        unsigned mb = mbuf[frame0 + f];
        #pragma unroll
        for (int j = 0; j < NJ; ++j)
            hv[j] = (mb >> j & 1) ? hv[j] : 0.f;
        float acc[NP];
        acc[0] = ((hv[0]+hv[1]) + (hv[2]+hv[3])) + hv[4];
        acc[1] = (hv[5]+hv[6]) + (hv[11]+hv[12]);
        acc[2] = hv[5]+hv[7]+hv[9];
        acc[3] = hv[6]+hv[8]+hv[10];
        acc[4] = hv[11]+hv[13]+hv[15];
        acc[5] = hv[12]+hv[14]+hv[16];
        const unsigned pm[NP] = {0x1Fu, 0x1860u, 0x2A0u, 0x540u, 0xA800u, 0x15000u};
        #pragma unroll
        for (int p = 0; p < NP; ++p) {
            float cnt = (float)__popc(mb & pm[p]);
            s_pool[(f*NP+p)*TSTR + d] = __float2bfloat16(acc[p] / fmaxf(cnt, 1e-6f));
        }
    }
    bsync();   // B1

    // ---- Stage 2: tok (REGISTERS) + q,k,v (LDS), double-buffered B prefetch ----
    f32x4 tk0 = (f32x4)(0.f), tk1 = (f32x4)(0.f);       // tok fragments (resid)
    {
        short8v bA[4], bB[4];
        #pragma unroll
        for (int ks = 0; ks < 4; ++ks) bA[ks] = ldB(wgt + WS_WP, w, ks, lane);
        #pragma unroll
        for (int ks = 0; ks < 4; ++ks) bB[ks] = ldB(wgt + WS_WC, w, ks, lane);   // q
        // tok (bA) -> registers, no bias (folded in stage 4)
        #pragma unroll
        for (int ks = 0; ks < 4; ++ks) {
            tk0 = MFMA(ldsA(s_pool, 0, ks, lane), bA[ks], tk0);
            tk1 = MFMA(ldsA(s_pool, 1, ks, lane), bA[ks], tk1);
        }
        #pragma unroll
        for (int ks = 0; ks < 4; ++ks) bA[ks] = ldB(wgt + WS_WC, 8 + w, ks, lane);  // k
        const int col = w*16 + l15;
        // q (bB)
        {
            f32x4 a0 = (f32x4)(0.f), a1 = (f32x4)(0.f);
            #pragma unroll
            for (int ks = 0; ks < 4; ++ks) {
                a0 = MFMA(ldsA(s_pool, 0, ks, lane), bB[ks], a0);
                a1 = MFMA(ldsA(s_pool, 1, ks, lane), bB[ks], a1);
            }
            st24(s_q, a0, a1, bc[w*16 + l15], col, lhi);
        }
        #pragma unroll
        for (int ks = 0; ks < 4; ++ks) bB[ks] = ldB(wgt + WS_WC, 16 + w, ks, lane); // v
        // k (bA)
        {
            f32x4 a0 = (f32x4)(0.f), a1 = (f32x4)(0.f);
            #pragma unroll
            for (int ks = 0; ks < 4; ++ks) {
                a0 = MFMA(ldsA(s_pool, 0, ks, lane), bA[ks], a0);
                a1 = MFMA(ldsA(s_pool, 1, ks, lane), bA[ks], a1);
            }
            st24(s_k, a0, a1, bc[(8+w)*16 + l15], col, lhi);
        }
        // v (bB)
        {
            f32x4 a0 = (f32x4)(0.f), a1 = (f32x4)(0.f);
            #pragma unroll
            for (int ks = 0; ks < 4; ++ks) {
                a0 = MFMA(ldsA(s_pool, 0, ks, lane), bB[ks], a0);
                a1 = MFMA(ldsA(s_pool, 1, ks, lane), bB[ks], a1);
            }
            st24(s_v, a0, a1, bc[(16+w)*16 + l15], col, lhi);
        }
    }
    bsync();   // B2

    // ---- Stage 3 (ALL 8 waves): wave pair (w, w+4) splits frame fq = w&3 by
    //      heads: hsel = w>>2 owns heads {2hsel, 2hsel+1} and cols [64hsel, 64hsel+64).
    //      Column ranges disjoint between the two waves -> intra-wave WFENCE only. ----
    {
        const int fq   = w & 3;
        const int hsel = w >> 2;
        float* s_pr = s_probs + fq*(NH*NP*NP);
        const int arow = (fq*NP + (l15 > 5 ? 5 : l15))*TSTR + (lhi << 3);
        #pragma unroll
        for (int hh = 0; hh < 2; ++hh) {
            const int h = hsel*2 + hh;
            short8v qa = *reinterpret_cast<const short8v*>(s_q + arow + h*32);
            short8v kb = *reinterpret_cast<const short8v*>(s_k + arow + h*32);
            f32x4 c = MFMA(qa, kb, (f32x4)(0.f));
            #pragma unroll
            for (int j = 0; j < 4; ++j) {
                int q = lhi*4 + j;
                float sc  = c[j] * 0.17677669529663688f;     // 1/sqrt(32)
                float scm = (l15 < NP) ? sc : -1e30f;
                scm = fmaxf(scm, __shfl_xor(scm, 1));
                scm = fmaxf(scm, __shfl_xor(scm, 2));
                scm = fmaxf(scm, __shfl_xor(scm, 4));
                scm = fmaxf(scm, __shfl_xor(scm, 8));
                float e = (l15 < NP) ? __expf(sc - scm) : 0.f;
                float den = e;
                den += __shfl_xor(den, 1);
                den += __shfl_xor(den, 2);
                den += __shfl_xor(den, 4);
                den += __shfl_xor(den, 8);
                if (q < NP && l15 < NP)
                    s_pr[(h*NP + q)*NP + l15] = e / den;
            }
        }
        WFENCE();   // own-head P visible within wave
        // PV: lane owns col c = 64*hsel + lane; head h = hsel*2 + (lane>>5).
        {
            const int c = hsel*64 + lane;
            const int h = hsel*2 + (lane >> 5);
            const float* pr = s_pr + h*NP*NP;
            float vv[NP];
            #pragma unroll
            for (int pk = 0; pk < NP; ++pk)
                vv[pk] = bf2f(*reinterpret_cast<const unsigned short*>(&s_v[(fq*NP+pk)*TSTR + c]));
            #pragma unroll
            for (int qi = 0; qi < NP; ++qi) {
                const float* pq = pr + qi*NP;
                float o = pq[0]*vv[0]+pq[1]*vv[1]+pq[2]*vv[2]
                        + pq[3]*vv[3]+pq[4]*vv[4]+pq[5]*vv[5];
                s_q[(fq*NP+qi)*TSTR + c] = __float2bfloat16(o);   // o over dead q cols
            }
        }
    }
    bsync();   // B3

    // ---- part_importance (24 threads) + Stage 4: y = o@Wo^T + (bp+bo) + tok ----
    if (tid < NG*NP) {
        int f = tid / NP, pk = tid - f*NP;
        const float* pr = s_probs + f*(NH*NP*NP);
        float s = 0.f;
        #pragma unroll
        for (int h = 0; h < NH; ++h)
            #pragma unroll
            for (int q = 0; q < NP; ++q)
                s += pr[(h*NP+q)*NP + pk];
        out[(long)NBT*NP*ND + (frame0+f)*NP + pk] = s * (1.f/24.f);
    }
    {
        short8v bo[4];
        #pragma unroll
        for (int ks = 0; ks < 4; ++ks) bo[ks] = ldB(wgt + WS_WO, w, ks, lane);
        f32x4 a0 = (f32x4)(0.f), a1 = (f32x4)(0.f);
        #pragma unroll
        for (int ks = 0; ks < 4; ++ks) {
            a0 = MFMA(ldsA(s_q, 0, ks, lane), bo[ks], a0);
            a1 = MFMA(ldsA(s_q, 1, ks, lane), bo[ks], a1);
        }
        int col = w*16 + l15;
        float bb = b_proj[col] + b_out[col];
        #pragma unroll
        for (int j = 0; j < 4; ++j) {
            int r0 = lhi*4 + j;
            s_y[r0*YSTR + col] = a0[j] + tk0[j] + bb;
            int r1 = 16 + lhi*4 + j;
            if (r1 < NTOK) s_y[r1*YSTR + col] = a1[j] + tk1[j] + bb;
        }
    }
    bsync();   // B4

    // ---- Stage 5: fused LayerNorm + store (wave w owns tokens 3w..3w+2) ----
    {
        const int c0 = lane*2;
        float2 g2 = *reinterpret_cast<const float2*>(ln_g + c0);
        float2 b2 = *reinterpret_cast<const float2*>(ln_b + c0);
        #pragma unroll
        for (int ti = 0; ti < 3; ++ti) {
            int token = w*3 + ti;
            float2 v = *reinterpret_cast<const float2*>(s_y + token*YSTR + c0);
            float s  = v.x + v.y;
            float s2 = v.x*v.x + v.y*v.y;
            s  += __shfl_xor(s, 1);  s  += __shfl_xor(s, 2);
            s  += __shfl_xor(s, 4);  s  += __shfl_xor(s, 8);
            s  += __shfl_xor(s, 16); s  += __shfl_xor(s, 32);
            s2 += __shfl_xor(s2, 1); s2 += __shfl_xor(s2, 2);
            s2 += __shfl_xor(s2, 4); s2 += __shfl_xor(s2, 8);
            s2 += __shfl_xor(s2, 16); s2 += __shfl_xor(s2, 32);
            float mean = s * (1.f/128.f);
            float rinv = rsqrtf(s2 * (1.f/128.f) - mean*mean + 1e-5f);
            float2 r;
            r.x = (v.x - mean)*rinv*g2.x + b2.x;
            r.y = (v.y - mean)*rinv*g2.y + b2.y;
            *reinterpret_cast<float2*>(out + (frame0*NP + token)*(long)ND + c0) = r;
        }
    }
}

extern "C" void kernel_launch(void* const* d_in, const int* in_sizes, int n_in,
                              void* d_out, int out_size, void* d_ws, size_t ws_size,
                              hipStream_t stream) {
    const float* h_joint = (const float*)d_in[0];
    const float* mask    = (const float*)d_in[1];
    const float* W_proj  = (const float*)d_in[2];
    const float* b_proj  = (const float*)d_in[3];
    const float* W_in    = (const float*)d_in[4];
    const float* b_in    = (const float*)d_in[5];
    const float* W_out   = (const float*)d_in[6];
    const float* b_out   = (const float*)d_in[7];
    const float* ln_g    = (const float*)d_in[8];
    const float* ln_b    = (const float*)d_in[9];
    float* out = (float*)d_out;
    bf16*     wgt  = (bf16*)d_ws;
    float*    bc   = (float*)((char*)d_ws + WS_BC);
    unsigned* mbuf = (unsigned*)((char*)d_ws + WS_MB);

    hipLaunchKernelGGL(prep, dim3(640), dim3(128), 0, stream,
                       W_proj, W_in, W_out, b_proj, b_in, mask, wgt, bc, mbuf);
    hipLaunchKernelGGL(bpa_fused, dim3(GRID), dim3(NTHR), 0, stream,
                       h_joint, wgt, bc, mbuf, b_proj, b_out, ln_g, ln_b, out);
}